// Round 9
// baseline (22.753 us; speedup 1.0000x reference)
//
#include <hip/hip_runtime.h>
#include <hip/hip_bf16.h>
#include <math.h>

#define IN_DIM 512
#define NC 100
#define NN 63
#define NE 16
#define BATCH 8192
#define XP 516   // padded x row stride in floats (516 mod 32 = 4 -> 2-way-free gathers)
#define RP 132   // padded red row stride (132 mod 32 = 4 -> breaks 16-bank write aliasing)

typedef __attribute__((ext_vector_type(8))) short bf16x8;
typedef __attribute__((ext_vector_type(4))) float f32x4;

static __device__ __forceinline__ ushort bf16_bits(__hip_bfloat16 h) {
  union { __hip_bfloat16 b; ushort u; } cv; cv.b = h; return cv.u;
}

// ---------------- Kernel 1: fused prep = B-fragments + per-node argmax (verbatim r8)
__global__ __launch_bounds__(256) void prep_kernel(
    const float* __restrict__ T, const float* __restrict__ L,
    ushort* __restrict__ Bfrag, float* __restrict__ tmax, int* __restrict__ dstar) {
  const int tid = threadIdx.x;
  const int bid = blockIdx.x;

  // --- L -> B-fragments [kc][hl][cf][lane][8] bf16 hi/lo ---
  {
    const int i = bid * 256 + tid;  // 0..262143
    const int j = i & 7;
    const int lane = (i >> 3) & 63;
    const int cf = (i >> 9) & 7;
    const int hl = (i >> 12) & 1;
    const int kc = i >> 13;
    const int k = kc * 32 + (lane >> 4) * 8 + j;
    const int c = cf * 16 + (lane & 15);
    const float val = (c < NC) ? L[(size_t)k * NC + c] : 0.0f;
    const __hip_bfloat16 hb = __float2bfloat16(val);
    ushort outv;
    if (hl == 0) {
      outv = bf16_bits(hb);
    } else {
      const __hip_bfloat16 lb = __float2bfloat16(val - __bfloat162float(hb));
      outv = bf16_bits(lb);
    }
    Bfrag[i] = outv;
  }

  // --- per-node argmax/max over IN_DIM: wave 0 of blocks 0..1007 ---
  if (bid < NE * NN && tid < 64) {
    const float4* row = reinterpret_cast<const float4*>(T + (size_t)bid * IN_DIM);
    const int lane = tid;
    float best = -INFINITY;
    int bidx = 0;
#pragma unroll
    for (int i = 0; i < 2; ++i) {
      const int f4 = lane + 64 * i;
      const float4 v = row[f4];
      const int base = f4 * 4;
      if (v.x > best) { best = v.x; bidx = base; }
      if (v.y > best) { best = v.y; bidx = base + 1; }
      if (v.z > best) { best = v.z; bidx = base + 2; }
      if (v.w > best) { best = v.w; bidx = base + 3; }
    }
#pragma unroll
    for (int off = 32; off; off >>= 1) {
      const float ov = __shfl_xor(best, off);
      const int oi = __shfl_xor(bidx, off);
      if (ov > best || (ov == best && oi < bidx)) { best = ov; bidx = oi; }
    }
    if (lane == 0) {
      tmax[bid] = best;
      dstar[bid] = bidx;
    }
  }
}

// ---------------- Kernel F: 32 rows/block, 8 waves; packed-table, wide LDS reads ----
__global__ __launch_bounds__(512, 2) void forest_fused_kernel(
    const float* __restrict__ x, const ushort* __restrict__ Bfrag,
    const float* __restrict__ tmaxg, const int* __restrict__ dstarg,
    float* __restrict__ out) {
  __shared__ __align__(16) float xl[32 * XP];        // 66048 B
  __shared__ __align__(16) int2 tds[NE * 64];        // 8192 B (entry 0/est unused; +1 shift)
  __shared__ __align__(16) float red[8 * 16 * RP];   // 67584 B (no xl alias)
  const int tid = threadIdx.x;
  const int b0 = blockIdx.x * 32;
  const int w = tid >> 6, lane = tid & 63;

  // ---- stage 32 x rows (f32 exact) + packed node table ----
  {
    const float4* xg = reinterpret_cast<const float4*>(x + (size_t)b0 * IN_DIM);
#pragma unroll
    for (int i = 0; i < 8; ++i) {
      const int idx = tid + i * 512;    // 0..4095
      const int r = idx >> 7, c4 = idx & 127;
      *reinterpret_cast<float4*>(&xl[r * XP + c4 * 4]) = xg[r * 128 + c4];
    }
    for (int i = tid; i < NE * NN; i += 512) {
      const int e = (i * 1041) >> 16;   // i/63 exact for i<1008
      const int n = i - e * 63;
      tds[e * 64 + 1 + n] = make_int2(dstarg[i], __float_as_int(tmaxg[i]));
    }
  }
  __syncthreads();

  const int r = lane & 15;
  const int lgq = lane >> 4;
  const float* xr0 = &xl[r * XP];
  const float* xr1 = &xl[(r + 16) * XP];
  const bf16x8* bf = reinterpret_cast<const bf16x8*>(Bfrag);

  f32x4 acc0[8], acc1[8];
#pragma unroll
  for (int cf = 0; cf < 8; ++cf) { acc0[cf] = (f32x4)0.0f; acc1[cf] = (f32x4)0.0f; }

  for (int t = 0; t < 4; ++t) {
    const int kc = w * 4 + t;
    const int e = kc >> 1;
    const int lg = (kc & 1) * 4 + lgq;

    // ---- issue 16 B loads up front; A-gen x2 hides L2 latency ----
    const size_t bbase = (size_t)kc * 1024;
    bf16x8 BH[8], BL[8];
#pragma unroll
    for (int cf = 0; cf < 8; ++cf) {
      BH[cf] = bf[bbase + (size_t)cf * 64 + lane];
      BL[cf] = bf[bbase + 512 + (size_t)cf * 64 + lane];
    }

    // ---- packed table reads (7 LDS instrs; shared across both row-tiles) ----
    const int2* tb = &tds[e * 64];
    const int2 T1 = tb[1];                  // node 0
    const int2 T2 = tb[2 + (lg >> 2)];      // node 1+(lg>>2)
    const int2 T3 = tb[4 + (lg >> 1)];      // node 3+(lg>>1)
    const int2 T4 = tb[8 + lg];             // node 7+lg
    const int4 P5 = *reinterpret_cast<const int4*>(&tb[16 + 2 * lg]);  // nodes 15+2lg, +1
    const int4 Q0 = *reinterpret_cast<const int4*>(&tb[32 + 4 * lg]);  // nodes 31+4lg, +1
    const int4 Q1 = *reinterpret_cast<const int4*>(&tb[34 + 4 * lg]);  // nodes 33+4lg, +1

    bf16x8 Ah, Al;
    // A-gen for one row (verbatim r8 math, table values from registers)
    auto agen = [&](const float* xr) {
      const float s1 = floorf(__int_as_float(T1.y) - xr[T1.x]);
      const float s2 = floorf(__int_as_float(T2.y) - xr[T2.x]);
      const float s3 = floorf(__int_as_float(T3.y) - xr[T3.x]);
      const float s4 = floorf(__int_as_float(T4.y) - xr[T4.x]);
      const float s5a = floorf(__int_as_float(P5.y) - xr[P5.x]);
      const float s5b = floorf(__int_as_float(P5.w) - xr[P5.z]);
      const float s60 = floorf(__int_as_float(Q0.y) - xr[Q0.x]);
      const float s61 = floorf(__int_as_float(Q0.w) - xr[Q0.z]);
      const float s62 = floorf(__int_as_float(Q1.y) - xr[Q1.x]);
      const float s63 = floorf(__int_as_float(Q1.w) - xr[Q1.z]);
      const float f1 = ((lg >> 2) & 1) ? 1.0f - s1 : s1;
      const float f2 = ((lg >> 1) & 1) ? 1.0f - s2 : s2;
      const float f3 = (lg & 1) ? 1.0f - s3 : s3;
      const float stem = f1 * f2 * f3;
      const float qa = stem * s4, qb = stem * (1.0f - s4);
      const float w00 = qa * s5a, w01 = qa * (1.0f - s5a);
      const float w10 = qb * s5b, w11 = qb * (1.0f - s5b);
      float p[8];
      p[0] = w00 * s60; p[1] = w00 * (1.0f - s60);
      p[2] = w01 * s61; p[3] = w01 * (1.0f - s61);
      p[4] = w10 * s62; p[5] = w10 * (1.0f - s62);
      p[6] = w11 * s63; p[7] = w11 * (1.0f - s63);
      union { ushort u[8]; bf16x8 v; } H, Lo;
#pragma unroll
      for (int i2 = 0; i2 < 8; ++i2) {
        const __hip_bfloat16 hb = __float2bfloat16(p[i2]);
        const float hf = __bfloat162float(hb);
        H.u[i2] = bf16_bits(hb);
        Lo.u[i2] = bf16_bits(__float2bfloat16(p[i2] - hf));
      }
      Ah = H.v; Al = Lo.v;
    };

    agen(xr0);
#pragma unroll
    for (int cf = 0; cf < 8; ++cf) {
      acc0[cf] = __builtin_amdgcn_mfma_f32_16x16x32_bf16(Ah, BH[cf], acc0[cf], 0, 0, 0);
      acc0[cf] = __builtin_amdgcn_mfma_f32_16x16x32_bf16(Al, BH[cf], acc0[cf], 0, 0, 0);
      acc0[cf] = __builtin_amdgcn_mfma_f32_16x16x32_bf16(Ah, BL[cf], acc0[cf], 0, 0, 0);
      acc0[cf] = __builtin_amdgcn_mfma_f32_16x16x32_bf16(Al, BL[cf], acc0[cf], 0, 0, 0);
    }
    agen(xr1);
#pragma unroll
    for (int cf = 0; cf < 8; ++cf) {
      acc1[cf] = __builtin_amdgcn_mfma_f32_16x16x32_bf16(Ah, BH[cf], acc1[cf], 0, 0, 0);
      acc1[cf] = __builtin_amdgcn_mfma_f32_16x16x32_bf16(Al, BH[cf], acc1[cf], 0, 0, 0);
      acc1[cf] = __builtin_amdgcn_mfma_f32_16x16x32_bf16(Ah, BL[cf], acc1[cf], 0, 0, 0);
      acc1[cf] = __builtin_amdgcn_mfma_f32_16x16x32_bf16(Al, BL[cf], acc1[cf], 0, 0, 0);
    }
  }

  // ---- epilogue: two passes through padded red; float4 partial reads ----
  const int rlo = (lane >> 4) * 4;
  const int cl = lane & 15;
  const int rr = tid >> 5;   // 0..15
  const int cg = tid & 31;   // 4 cols each

  auto epi = [&](const f32x4 (&ac)[8], int rowbase) {
#pragma unroll
    for (int cf = 0; cf < 8; ++cf)
#pragma unroll
      for (int jj = 0; jj < 4; ++jj)
        red[(w * 16 + rlo + jj) * RP + cf * 16 + cl] = ac[cf][jj];
    __syncthreads();
    float v[4] = {0.0f, 0.0f, 0.0f, 0.0f};
#pragma unroll
    for (int pw = 0; pw < 8; ++pw) {
      const float4 rv =
          *reinterpret_cast<const float4*>(&red[(pw * 16 + rr) * RP + cg * 4]);
      v[0] += rv.x; v[1] += rv.y; v[2] += rv.z; v[3] += rv.w;
    }
    float m = -INFINITY;
#pragma unroll
    for (int j = 0; j < 4; ++j)
      if (cg * 4 + j < NC) m = fmaxf(m, v[j]);
#pragma unroll
    for (int off = 1; off < 32; off <<= 1) m = fmaxf(m, __shfl_xor(m, off));
    float ev[4];
    float ss = 0.0f;
#pragma unroll
    for (int j = 0; j < 4; ++j) {
      ev[j] = (cg * 4 + j < NC) ? __expf(v[j] - m) : 0.0f;
      ss += ev[j];
    }
#pragma unroll
    for (int off = 1; off < 32; off <<= 1) ss += __shfl_xor(ss, off);
    const float inv = 1.0f / ss;
    if (cg < 25) {
      float* orow = out + (size_t)(b0 + rowbase + rr) * NC + cg * 4;
      *reinterpret_cast<float4*>(orow) =
          make_float4(ev[0] * inv, ev[1] * inv, ev[2] * inv, ev[3] * inv);
    }
  };

  epi(acc0, 0);
  __syncthreads();   // pass-0 reads done before pass-1 overwrites red
  epi(acc1, 16);
}

extern "C" void kernel_launch(void* const* d_in, const int* in_sizes, int n_in,
                              void* d_out, int out_size, void* d_ws, size_t ws_size,
                              hipStream_t stream) {
  const float* x = (const float*)d_in[0];  // (8192, 512)
  const float* T = (const float*)d_in[1];  // (16, 63, 512)
  const float* L = (const float*)d_in[2];  // (16, 64, 100)
  float* out = (float*)d_out;              // (8192, 100)

  char* ws = (char*)d_ws;
  ushort* Bfrag = (ushort*)ws;              // 262144 bf16 = 524288 B
  float* tmax = (float*)(ws + 524288);      // 1008 f32
  int* dstar = (int*)(ws + 528384);         // 1008 i32

  prep_kernel<<<1024, 256, 0, stream>>>(T, L, Bfrag, tmax, dstar);
  forest_fused_kernel<<<BATCH / 32, 512, 0, stream>>>(x, Bfrag, tmax, dstar, out);
}